// Round 1
// 1110.749 us; speedup vs baseline: 1.0650x; 1.0650x over previous
//
#include <hip/hip_runtime.h>
#include <stdint.h>

// B=1, S=2048, D=4096, H=32, HD=128. fp32 inputs/outputs, bf16 intermediates.
// Round 4:
//  - gemm_bt: global_load_lds width=16 staging (m93->m97 ladder step).
//  - fattn: KVBLK=64 (LDS 104960 -> ~63KB => 2 blocks/CU), mask-aware tile
//    skip (strict-upper valid region => block qb only needs kt >= qb; the
//    block containing row S-1 processes all tiles for exactness), setprio
//    around MFMA clusters (2 blocks/CU -> phase-diverse waves).
// Workspace (96 MB):
//   [ 0M,32M)  Wt  : transposed+bf16 weight scratch (4096x4096), reused 4x
//   [32M,48M)  Xbf : hidden_state bf16; reused as AO after attention
//   [48M,64M)  Q   [64M,80M) K  (2048x4096)   [80M,96M) VT (4096x2048)

#define SS 2048
#define DD 4096
#define NH 32
#define HD 128
#define NEGV -1000000000.0f
#define LDP 136  // Q/K row stride (128 + 8 pad): 272B, 16B-aligned rows
#define LDV 72   // Vt/P row stride (64 + 8 pad): 144B, 16B-aligned rows

typedef __bf16 bf16x8 __attribute__((ext_vector_type(8)));
typedef float f32x4 __attribute__((ext_vector_type(4)));

#define GLDS16(gp, lp)                                                        \
    __builtin_amdgcn_global_load_lds(                                         \
        (__attribute__((address_space(1))) uint32_t*)(uintptr_t)(gp),         \
        (__attribute__((address_space(3))) uint32_t*)(uintptr_t)(lp), 16, 0, 0)

__device__ __forceinline__ float bf2f(uint16_t u) {
    union { uint32_t i; float f; } v; v.i = ((uint32_t)u) << 16; return v.f;
}
__device__ __forceinline__ uint16_t f2bf(float f) {
    union { float f; uint32_t i; } v; v.f = f;
    uint32_t x = v.i;
    uint32_t r = (x + 0x7fffu + ((x >> 16) & 1u)) >> 16;
    return (uint16_t)r;
}

__device__ __forceinline__ void storeOut(float* C, size_t i, float v) { C[i] = v; }
__device__ __forceinline__ void storeOut(uint16_t* C, size_t i, float v) { C[i] = f2bf(v); }

__global__ void xconv_kernel(const float* __restrict__ in, uint16_t* __restrict__ out) {
    int i = blockIdx.x * blockDim.x + threadIdx.x;
    const float4* in4 = (const float4*)in;
    float4 a = in4[2 * i], b = in4[2 * i + 1];
    uint4 o;
    o.x = (uint32_t)f2bf(a.x) | ((uint32_t)f2bf(a.y) << 16);
    o.y = (uint32_t)f2bf(a.z) | ((uint32_t)f2bf(a.w) << 16);
    o.z = (uint32_t)f2bf(b.x) | ((uint32_t)f2bf(b.y) << 16);
    o.w = (uint32_t)f2bf(b.z) | ((uint32_t)f2bf(b.w) << 16);
    ((uint4*)out)[i] = o;
}

// out[n][k] = bf16(in[k][n]), 4096x4096
__global__ void wtrans_kernel(const float* __restrict__ in,
                              uint16_t* __restrict__ out) {
    __shared__ uint16_t tile[32][33];
    int bx = blockIdx.x * 32, by = blockIdx.y * 32;
    int tx = threadIdx.x, ty = threadIdx.y;
    #pragma unroll
    for (int i = 0; i < 32; i += 8)
        tile[ty + i][tx] = f2bf(in[(size_t)(by + ty + i) * DD + bx + tx]);
    __syncthreads();
    #pragma unroll
    for (int i = 0; i < 32; i += 8)
        out[(size_t)(bx + ty + i) * DD + by + tx] = tile[tx][ty + i];
}

// C[M][N] = A[M][K] @ Bt[N][K]^T (bf16 in, fp32 acc). M,N,K multiples of 128.
template <typename OutT>
__global__ __launch_bounds__(256) void gemm_bt(const uint16_t* __restrict__ A,
                                               const uint16_t* __restrict__ Bt,
                                               OutT* __restrict__ C,
                                               int M, int N, int K) {
    __shared__ __attribute__((aligned(16))) uint16_t sA[128 * 32];
    __shared__ __attribute__((aligned(16))) uint16_t sB[128 * 32];
    int t = threadIdx.x;
    int lane = t & 63, w = t >> 6;
    int wm = (w >> 1) * 64, wn = (w & 1) * 64;
    int rowBase = blockIdx.y * 128, colBase = blockIdx.x * 128;
    f32x4 acc[4][4] = {};

    int lr = lane & 15;
    int kq = (lane >> 4) * 8;

    for (int k0 = 0; k0 < K; k0 += 32) {
        __syncthreads();
        #pragma unroll
        for (int p = 0; p < 2; ++p) {
            int c = p * 256 + t;
            int r = c >> 2;
            int cc = (c & 3) * 8;
            // LDS dest = wave-uniform base + lane*16B (layout is contiguous:
            // element offset c*8 == r*32+cc), global src is per-lane.
            GLDS16(&A[(size_t)(rowBase + r) * K + k0 + cc], &sA[c * 8]);
            GLDS16(&Bt[(size_t)(colBase + r) * K + k0 + cc], &sB[c * 8]);
        }
        __syncthreads();

        bf16x8 af[4], bfr[4];
        #pragma unroll
        for (int i = 0; i < 4; ++i) {
            af[i]  = *(const bf16x8*)(&sA[(wm + i * 16 + lr) * 32 + kq]);
            bfr[i] = *(const bf16x8*)(&sB[(wn + i * 16 + lr) * 32 + kq]);
        }
        #pragma unroll
        for (int mt = 0; mt < 4; ++mt)
            #pragma unroll
            for (int nt = 0; nt < 4; ++nt)
                acc[mt][nt] = __builtin_amdgcn_mfma_f32_16x16x32_bf16(
                    af[mt], bfr[nt], acc[mt][nt], 0, 0, 0);
    }

    int q = lane >> 4;
    #pragma unroll
    for (int mt = 0; mt < 4; ++mt)
        #pragma unroll
        for (int nt = 0; nt < 4; ++nt)
            #pragma unroll
            for (int r = 0; r < 4; ++r) {
                int row = rowBase + wm + mt * 16 + q * 4 + r;
                int col = colBase + wn + nt * 16 + lr;
                storeOut(C, (size_t)row * N + col, acc[mt][nt][r]);
            }
}

// RoPE in-place on bf16 Q and K; cos/sin fp32 (1,S,D); rotate-half at 2048.
__global__ void rope_kernel(uint16_t* __restrict__ q, uint16_t* __restrict__ k,
                            const float* __restrict__ cosb,
                            const float* __restrict__ sinb) {
    int idx = blockIdx.x * blockDim.x + threadIdx.x;
    int s = idx >> 11;
    int d = idx & 2047;
    size_t i0 = (size_t)s * DD + d, i1 = i0 + 2048;
    float c0 = cosb[i0], c1 = cosb[i1];
    float s0 = sinb[i0], s1 = sinb[i1];
    float q0 = bf2f(q[i0]), q1 = bf2f(q[i1]);
    q[i0] = f2bf(q0 * c0 - q1 * s0);
    q[i1] = f2bf(q1 * c1 + q0 * s1);
    float k0 = bf2f(k[i0]), k1 = bf2f(k[i1]);
    k[i0] = f2bf(k0 * c0 - k1 * s0);
    k[i1] = f2bf(k1 * c1 + k0 * s1);
}

// Flash attention: block = (head, 64 q-rows), 4 waves, K-tiles of 64.
// Valid score region is STRICT UPPER (kk > qrow): block qb only needs tiles
// kt >= qb; skipped tiles are exactly 0 after softmax (exp(-1e9 - m) == 0 in
// fp32) for every row with >=1 valid entry. Row S-1 has none, so the last
// block processes all tiles (bitwise-matching the full computation there).
__global__ __launch_bounds__(256) void fattn_kernel(
    const uint16_t* __restrict__ Q, const uint16_t* __restrict__ K,
    const uint16_t* __restrict__ VT, const float* __restrict__ mask,
    uint16_t* __restrict__ O)
{
    __shared__ __attribute__((aligned(16))) uint16_t sQ[64 * LDP];
    __shared__ __attribute__((aligned(16))) uint16_t sK[64 * LDP];  // reused as sO
    __shared__ __attribute__((aligned(16))) uint16_t sVt[HD * LDV];
    __shared__ __attribute__((aligned(16))) uint16_t sP[64 * LDV];
    __shared__ float sAlpha[64];
    __shared__ float sL[64];

    int h = blockIdx.y, q0 = blockIdx.x * 64;
    int base = h * HD;
    int t = threadIdx.x;
    int lane = t & 63, w = t >> 6;
    int lr = lane & 15, quad = lane >> 4;
    int mw = w * 16;

    for (int c = t; c < 64 * 16; c += 256) {
        int m = c >> 4, dc = (c & 15) * 8;
        *(uint4*)(&sQ[m * LDP + dc]) =
            *(const uint4*)(&Q[(size_t)(q0 + m) * DD + base + dc]);
    }

    f32x4 oacc[2][4] = {};   // [dt][nt] : rows dd=(2w+dt)*16+quad*4+reg, cols m=nt*16+lr
    float m_pr[4], l_run[4];
    #pragma unroll
    for (int r = 0; r < 4; ++r) { m_pr[r] = -3.0e38f; l_run[r] = 0.f; }

    int kt_lo = (q0 == SS - 64) ? 0 : blockIdx.x;  // tile skip (see header)
    for (int kt = kt_lo; kt < SS / 64; ++kt) {
        __syncthreads();
        // stage K tile: 64 rows x 128 cols
        for (int c = t; c < 64 * 16; c += 256) {
            int r = c >> 4, dc = (c & 15) * 8;
            *(uint4*)(&sK[r * LDP + dc]) =
                *(const uint4*)(&K[(size_t)(kt * 64 + r) * DD + base + dc]);
        }
        // stage Vt tile: 128 rows x 64 cols
        for (int c = t; c < 128 * 8; c += 256) {
            int r = c >> 3, dc = (c & 7) * 8;
            *(uint4*)(&sVt[r * LDV + dc]) =
                *(const uint4*)(&VT[(size_t)(base + r) * SS + kt * 64 + dc]);
        }
        __syncthreads();

        // QK^T: this wave owns q-rows mw..mw+15, all 64 kk of the tile
        f32x4 sacc[4] = {};
        __builtin_amdgcn_s_setprio(1);
        #pragma unroll
        for (int kc = 0; kc < 4; ++kc) {
            bf16x8 af = *(const bf16x8*)(&sQ[(mw + lr) * LDP + kc * 32 + quad * 8]);
            #pragma unroll
            for (int nt = 0; nt < 4; ++nt) {
                bf16x8 bfr = *(const bf16x8*)(&sK[(nt * 16 + lr) * LDP + kc * 32 + quad * 8]);
                sacc[nt] = __builtin_amdgcn_mfma_f32_16x16x32_bf16(af, bfr, sacc[nt], 0, 0, 0);
            }
        }
        __builtin_amdgcn_s_setprio(0);

        // scores: scale + attn_mask + anti-causal tri (kk <= qrow -> +NEG)
        float sc[4][4];
        #pragma unroll
        for (int nt = 0; nt < 4; ++nt) {
            int kk = kt * 64 + nt * 16 + lr;
            #pragma unroll
            for (int r = 0; r < 4; ++r) {
                int qrow = q0 + mw + quad * 4 + r;
                float s = sacc[nt][r] * 0.015625f + mask[(size_t)qrow * SS + kk];
                if (kk <= qrow) s += NEGV;
                sc[nt][r] = s;
            }
        }

        float mnew[4], alpha[4];
        #pragma unroll
        for (int r = 0; r < 4; ++r) {
            float mx = sc[0][r];
            #pragma unroll
            for (int nt = 1; nt < 4; ++nt) mx = fmaxf(mx, sc[nt][r]);
            #pragma unroll
            for (int off = 1; off < 16; off <<= 1)
                mx = fmaxf(mx, __shfl_xor(mx, off));
            mnew[r] = fmaxf(m_pr[r], mx);
            alpha[r] = __expf(m_pr[r] - mnew[r]);
            m_pr[r] = mnew[r];
        }

        float ps[4] = {0.f, 0.f, 0.f, 0.f};
        #pragma unroll
        for (int nt = 0; nt < 4; ++nt) {
            #pragma unroll
            for (int r = 0; r < 4; ++r) {
                float p = __expf(sc[nt][r] - mnew[r]);
                ps[r] += p;
                sP[(mw + quad * 4 + r) * LDV + nt * 16 + lr] = f2bf(p);
            }
        }
        #pragma unroll
        for (int r = 0; r < 4; ++r) {
            #pragma unroll
            for (int off = 1; off < 16; off <<= 1)
                ps[r] += __shfl_xor(ps[r], off);
            l_run[r] = l_run[r] * alpha[r] + ps[r];
            if (lr == 0) sAlpha[mw + quad * 4 + r] = alpha[r];
        }
        __syncthreads();

        // O^T += VT_tile @ P^T ; wave owns dd-tiles 2w, 2w+1
        float a_col[4];
        #pragma unroll
        for (int nt = 0; nt < 4; ++nt) a_col[nt] = sAlpha[nt * 16 + lr];
        #pragma unroll
        for (int dt = 0; dt < 2; ++dt)
            #pragma unroll
            for (int nt = 0; nt < 4; ++nt)
                #pragma unroll
                for (int r = 0; r < 4; ++r)
                    oacc[dt][nt][r] *= a_col[nt];
        __builtin_amdgcn_s_setprio(1);
        #pragma unroll
        for (int kc = 0; kc < 2; ++kc) {
            bf16x8 bfr[4];
            #pragma unroll
            for (int nt = 0; nt < 4; ++nt)
                bfr[nt] = *(const bf16x8*)(&sP[(nt * 16 + lr) * LDV + kc * 32 + quad * 8]);
            #pragma unroll
            for (int dt = 0; dt < 2; ++dt) {
                bf16x8 af = *(const bf16x8*)(&sVt[((2 * w + dt) * 16 + lr) * LDV + kc * 32 + quad * 8]);
                #pragma unroll
                for (int nt = 0; nt < 4; ++nt)
                    oacc[dt][nt] = __builtin_amdgcn_mfma_f32_16x16x32_bf16(af, bfr[nt], oacc[dt][nt], 0, 0, 0);
            }
        }
        __builtin_amdgcn_s_setprio(0);
    }

    #pragma unroll
    for (int r = 0; r < 4; ++r)
        if (lr == 0) sL[mw + quad * 4 + r] = l_run[r];
    __syncthreads();

    // O^T regs -> sO (=sK) [m][dd] with 1/l scaling, then coalesced store
    float linv[4];
    #pragma unroll
    for (int nt = 0; nt < 4; ++nt) linv[nt] = 1.f / sL[nt * 16 + lr];
    #pragma unroll
    for (int dt = 0; dt < 2; ++dt) {
        int ddl = (2 * w + dt) * 16 + quad * 4;
        #pragma unroll
        for (int nt = 0; nt < 4; ++nt) {
            int ml = nt * 16 + lr;
            #pragma unroll
            for (int r = 0; r < 4; ++r)
                sK[ml * LDP + ddl + r] = f2bf(oacc[dt][nt][r] * linv[nt]);
        }
    }
    __syncthreads();
    for (int c = t; c < 64 * 16; c += 256) {
        int m = c >> 4, dc = (c & 15) * 8;
        *(uint4*)(&O[(size_t)(q0 + m) * DD + base + dc]) =
            *(const uint4*)(&sK[m * LDP + dc]);
    }
}

extern "C" void kernel_launch(void* const* d_in, const int* in_sizes, int n_in,
                              void* d_out, int out_size, void* d_ws, size_t ws_size,
                              hipStream_t stream) {
    const float* X    = (const float*)d_in[0];
    const float* mask = (const float*)d_in[1];
    const float* cosb = (const float*)d_in[2];
    const float* sinb = (const float*)d_in[3];
    const float* wq   = (const float*)d_in[4];
    const float* wk   = (const float*)d_in[5];
    const float* wv   = (const float*)d_in[6];
    const float* wo   = (const float*)d_in[7];
    float* out = (float*)d_out;

    char* ws = (char*)d_ws;
    uint16_t* Wt  = (uint16_t*)ws;                            // 32 MB
    uint16_t* Xbf = (uint16_t*)(ws + (size_t)33554432);       // 16 MB
    uint16_t* Q   = Xbf + (size_t)SS * DD;
    uint16_t* Kb  = Q  + (size_t)SS * DD;
    uint16_t* VT  = Kb + (size_t)SS * DD;                     // [D][S]
    uint16_t* AO  = Xbf;  // X dead after VT gemm; reuse for attention output

    dim3 tgrid(DD / 32, DD / 32), tblock(32, 8);
    dim3 ggrid(DD / 128, SS / 128), gblock(256);

    xconv_kernel<<<(SS * DD) / (256 * 8), 256, 0, stream>>>(X, Xbf);

    wtrans_kernel<<<tgrid, tblock, 0, stream>>>(wq, Wt);
    gemm_bt<<<ggrid, gblock, 0, stream>>>(Xbf, Wt, Q, SS, DD, DD);
    wtrans_kernel<<<tgrid, tblock, 0, stream>>>(wk, Wt);
    gemm_bt<<<ggrid, gblock, 0, stream>>>(Xbf, Wt, Kb, SS, DD, DD);
    wtrans_kernel<<<tgrid, tblock, 0, stream>>>(wv, Wt);
    // VT[d][s] = sum_k Wv[k][d] * X[s][k]  (A = Wv^T rows, Bt = X rows)
    gemm_bt<<<dim3(SS / 128, DD / 128), gblock, 0, stream>>>(Wt, Xbf, VT, DD, SS, DD);

    rope_kernel<<<(SS * 2048) / 256, 256, 0, stream>>>(Q, Kb, cosb, sinb);

    fattn_kernel<<<dim3(SS / 64, NH), 256, 0, stream>>>(Q, Kb, VT, mask, AO);

    wtrans_kernel<<<tgrid, tblock, 0, stream>>>(wo, Wt);
    gemm_bt<<<ggrid, gblock, 0, stream>>>(AO, Wt, out, SS, DD, DD);
}

// Round 3
// 983.082 us; speedup vs baseline: 1.2033x; 1.1299x over previous
//
#include <hip/hip_runtime.h>
#include <stdint.h>

// B=1, S=2048, D=4096, H=32, HD=128. fp32 inputs/outputs, bf16 intermediates.
// Round 6 (= Round 5 resubmitted; prior bench was an infra failure):
//  - fattn: perfectly load-balanced pairing — each workgroup processes TWO
//    q-blocks {j, 29-j} (j<15) or {30, 31}, so all 512 blocks do 34-35 tiles.
//    Grid 512 = exactly 2 blocks/CU capacity. Mask tile staged to LDS via
//    coalesced float4 (kills 16 scalar global loads/lane/tile). XCD-grouped
//    block swizzle: each XCD's 64 blocks cover 4 heads (~4MB K/V = L2-fit).
//  - gemm_bt: unchanged (global_load_lds staging, m97 structure).
// Workspace (96 MB):
//   [ 0M,32M)  Wt  : transposed+bf16 weight scratch (4096x4096), reused 4x
//   [32M,48M)  Xbf : hidden_state bf16; reused as AO after attention
//   [48M,64M)  Q   [64M,80M) K  (2048x4096)   [80M,96M) VT (4096x2048)

#define SS 2048
#define DD 4096
#define NH 32
#define HD 128
#define NEGV -1000000000.0f
#define LDP 136  // Q/K row stride (128 + 8 pad): 272B, 16B-aligned rows
#define LDV 72   // Vt/P row stride (64 + 8 pad): 144B, 16B-aligned rows
#define LDM 68   // mask row stride in floats (64 + 4 pad)

typedef __bf16 bf16x8 __attribute__((ext_vector_type(8)));
typedef float f32x4 __attribute__((ext_vector_type(4)));

#define GLDS16(gp, lp)                                                        \
    __builtin_amdgcn_global_load_lds(                                         \
        (__attribute__((address_space(1))) uint32_t*)(uintptr_t)(gp),         \
        (__attribute__((address_space(3))) uint32_t*)(uintptr_t)(lp), 16, 0, 0)

__device__ __forceinline__ float bf2f(uint16_t u) {
    union { uint32_t i; float f; } v; v.i = ((uint32_t)u) << 16; return v.f;
}
__device__ __forceinline__ uint16_t f2bf(float f) {
    union { float f; uint32_t i; } v; v.f = f;
    uint32_t x = v.i;
    uint32_t r = (x + 0x7fffu + ((x >> 16) & 1u)) >> 16;
    return (uint16_t)r;
}

__device__ __forceinline__ void storeOut(float* C, size_t i, float v) { C[i] = v; }
__device__ __forceinline__ void storeOut(uint16_t* C, size_t i, float v) { C[i] = f2bf(v); }

__global__ void xconv_kernel(const float* __restrict__ in, uint16_t* __restrict__ out) {
    int i = blockIdx.x * blockDim.x + threadIdx.x;
    const float4* in4 = (const float4*)in;
    float4 a = in4[2 * i], b = in4[2 * i + 1];
    uint4 o;
    o.x = (uint32_t)f2bf(a.x) | ((uint32_t)f2bf(a.y) << 16);
    o.y = (uint32_t)f2bf(a.z) | ((uint32_t)f2bf(a.w) << 16);
    o.z = (uint32_t)f2bf(b.x) | ((uint32_t)f2bf(b.y) << 16);
    o.w = (uint32_t)f2bf(b.z) | ((uint32_t)f2bf(b.w) << 16);
    ((uint4*)out)[i] = o;
}

// out[n][k] = bf16(in[k][n]), 4096x4096
__global__ void wtrans_kernel(const float* __restrict__ in,
                              uint16_t* __restrict__ out) {
    __shared__ uint16_t tile[32][33];
    int bx = blockIdx.x * 32, by = blockIdx.y * 32;
    int tx = threadIdx.x, ty = threadIdx.y;
    #pragma unroll
    for (int i = 0; i < 32; i += 8)
        tile[ty + i][tx] = f2bf(in[(size_t)(by + ty + i) * DD + bx + tx]);
    __syncthreads();
    #pragma unroll
    for (int i = 0; i < 32; i += 8)
        out[(size_t)(bx + ty + i) * DD + by + tx] = tile[tx][ty + i];
}

// C[M][N] = A[M][K] @ Bt[N][K]^T (bf16 in, fp32 acc). M,N,K multiples of 128.
template <typename OutT>
__global__ __launch_bounds__(256) void gemm_bt(const uint16_t* __restrict__ A,
                                               const uint16_t* __restrict__ Bt,
                                               OutT* __restrict__ C,
                                               int M, int N, int K) {
    __shared__ __attribute__((aligned(16))) uint16_t sA[128 * 32];
    __shared__ __attribute__((aligned(16))) uint16_t sB[128 * 32];
    int t = threadIdx.x;
    int lane = t & 63, w = t >> 6;
    int wm = (w >> 1) * 64, wn = (w & 1) * 64;
    int rowBase = blockIdx.y * 128, colBase = blockIdx.x * 128;
    f32x4 acc[4][4] = {};

    int lr = lane & 15;
    int kq = (lane >> 4) * 8;

    for (int k0 = 0; k0 < K; k0 += 32) {
        __syncthreads();
        #pragma unroll
        for (int p = 0; p < 2; ++p) {
            int c = p * 256 + t;
            int r = c >> 2;
            int cc = (c & 3) * 8;
            GLDS16(&A[(size_t)(rowBase + r) * K + k0 + cc], &sA[c * 8]);
            GLDS16(&Bt[(size_t)(colBase + r) * K + k0 + cc], &sB[c * 8]);
        }
        __syncthreads();

        bf16x8 af[4], bfr[4];
        #pragma unroll
        for (int i = 0; i < 4; ++i) {
            af[i]  = *(const bf16x8*)(&sA[(wm + i * 16 + lr) * 32 + kq]);
            bfr[i] = *(const bf16x8*)(&sB[(wn + i * 16 + lr) * 32 + kq]);
        }
        #pragma unroll
        for (int mt = 0; mt < 4; ++mt)
            #pragma unroll
            for (int nt = 0; nt < 4; ++nt)
                acc[mt][nt] = __builtin_amdgcn_mfma_f32_16x16x32_bf16(
                    af[mt], bfr[nt], acc[mt][nt], 0, 0, 0);
    }

    int q = lane >> 4;
    #pragma unroll
    for (int mt = 0; mt < 4; ++mt)
        #pragma unroll
        for (int nt = 0; nt < 4; ++nt)
            #pragma unroll
            for (int r = 0; r < 4; ++r) {
                int row = rowBase + wm + mt * 16 + q * 4 + r;
                int col = colBase + wn + nt * 16 + lr;
                storeOut(C, (size_t)row * N + col, acc[mt][nt][r]);
            }
}

// RoPE in-place on bf16 Q and K; cos/sin fp32 (1,S,D); rotate-half at 2048.
__global__ void rope_kernel(uint16_t* __restrict__ q, uint16_t* __restrict__ k,
                            const float* __restrict__ cosb,
                            const float* __restrict__ sinb) {
    int idx = blockIdx.x * blockDim.x + threadIdx.x;
    int s = idx >> 11;
    int d = idx & 2047;
    size_t i0 = (size_t)s * DD + d, i1 = i0 + 2048;
    float c0 = cosb[i0], c1 = cosb[i1];
    float s0 = sinb[i0], s1 = sinb[i1];
    float q0 = bf2f(q[i0]), q1 = bf2f(q[i1]);
    q[i0] = f2bf(q0 * c0 - q1 * s0);
    q[i1] = f2bf(q1 * c1 + q0 * s1);
    float k0 = bf2f(k[i0]), k1 = bf2f(k[i1]);
    k[i0] = f2bf(k0 * c0 - k1 * s0);
    k[i1] = f2bf(k1 * c1 + k0 * s1);
}

// Flash attention: 512 workgroups, each = (head, pair of q-blocks), 4 waves,
// K-tiles of 64. Valid score region is STRICT UPPER (kk > qrow): q-block qb
// only needs tiles kt >= qb; skipped tiles are exactly 0 after softmax
// (exp(-1e9 - m) == 0 in fp32) for every row with >=1 valid entry. Row S-1
// has none, so qb=31 processes all tiles (bitwise-matching full compute).
// tiles(qb) = 32-qb (qb<31), 32 (qb=31). Pairs {j,29-j} -> 35 tiles each,
// {30,31} -> 34: perfectly balanced across exactly 2 blocks/CU capacity.
__global__ __launch_bounds__(256) void fattn_kernel(
    const uint16_t* __restrict__ Q, const uint16_t* __restrict__ K,
    const uint16_t* __restrict__ VT, const float* __restrict__ mask,
    uint16_t* __restrict__ O)
{
    __shared__ __attribute__((aligned(16))) uint16_t sQ[64 * LDP];
    __shared__ __attribute__((aligned(16))) uint16_t sK[64 * LDP];  // reused as sO
    __shared__ __attribute__((aligned(16))) uint16_t sVt[HD * LDV];
    __shared__ __attribute__((aligned(16))) uint16_t sP[64 * LDV];
    __shared__ __attribute__((aligned(16))) float sM[64 * LDM];
    __shared__ float sAlpha[64];
    __shared__ float sL[64];

    // XCD-grouped swizzle: phys p -> virt so each XCD's 64 blocks share 4 heads
    int p = blockIdx.x;
    int virt = (p & 7) * 64 + (p >> 3);
    int h = virt >> 4, j = virt & 15;
    int base = h * HD;
    int t = threadIdx.x;
    int lane = t & 63, w = t >> 6;
    int lr = lane & 15, quad = lane >> 4;
    int mw = w * 16;

    for (int item = 0; item < 2; ++item) {
        int qb = (j < 15) ? (item ? 29 - j : j) : (30 + item);
        int q0 = qb * 64;

        // stage Q for this q-block (sQ unread since well before last barrier)
        for (int c = t; c < 64 * 16; c += 256) {
            int m = c >> 4, dc = (c & 15) * 8;
            *(uint4*)(&sQ[m * LDP + dc]) =
                *(const uint4*)(&Q[(size_t)(q0 + m) * DD + base + dc]);
        }

        f32x4 oacc[2][4] = {};  // [dt][nt]: rows dd=(2w+dt)*16+quad*4+reg, cols m=nt*16+lr
        float m_pr[4], l_run[4];
        #pragma unroll
        for (int r = 0; r < 4; ++r) { m_pr[r] = -3.0e38f; l_run[r] = 0.f; }

        int kt_lo = (qb == 31) ? 0 : qb;
        for (int kt = kt_lo; kt < SS / 64; ++kt) {
            __syncthreads();
            // stage K tile: 64 rows x 128 cols
            for (int c = t; c < 64 * 16; c += 256) {
                int r = c >> 4, dc = (c & 15) * 8;
                *(uint4*)(&sK[r * LDP + dc]) =
                    *(const uint4*)(&K[(size_t)(kt * 64 + r) * DD + base + dc]);
            }
            // stage Vt tile: 128 rows x 64 cols
            for (int c = t; c < 128 * 8; c += 256) {
                int r = c >> 3, dc = (c & 7) * 8;
                *(uint4*)(&sVt[r * LDV + dc]) =
                    *(const uint4*)(&VT[(size_t)(base + r) * SS + kt * 64 + dc]);
            }
            // stage mask tile: 64 rows x 64 cols fp32, coalesced float4
            for (int c = t; c < 1024; c += 256) {
                int r = c >> 4, c4 = (c & 15) * 4;
                *(float4*)(&sM[r * LDM + c4]) =
                    *(const float4*)(&mask[(size_t)(q0 + r) * SS + kt * 64 + c4]);
            }
            __syncthreads();

            // QK^T: this wave owns q-rows mw..mw+15, all 64 kk of the tile
            f32x4 sacc[4] = {};
            __builtin_amdgcn_s_setprio(1);
            #pragma unroll
            for (int kc = 0; kc < 4; ++kc) {
                bf16x8 af = *(const bf16x8*)(&sQ[(mw + lr) * LDP + kc * 32 + quad * 8]);
                #pragma unroll
                for (int nt = 0; nt < 4; ++nt) {
                    bf16x8 bfr = *(const bf16x8*)(&sK[(nt * 16 + lr) * LDP + kc * 32 + quad * 8]);
                    sacc[nt] = __builtin_amdgcn_mfma_f32_16x16x32_bf16(af, bfr, sacc[nt], 0, 0, 0);
                }
            }
            __builtin_amdgcn_s_setprio(0);

            // scores: scale + attn_mask (LDS) + anti-causal tri (kk <= qrow -> +NEG)
            float sc[4][4];
            #pragma unroll
            for (int nt = 0; nt < 4; ++nt) {
                int kk = kt * 64 + nt * 16 + lr;
                #pragma unroll
                for (int r = 0; r < 4; ++r) {
                    int qrl = mw + quad * 4 + r;
                    float s = sacc[nt][r] * 0.015625f + sM[qrl * LDM + nt * 16 + lr];
                    if (kk <= q0 + qrl) s += NEGV;
                    sc[nt][r] = s;
                }
            }

            float mnew[4], alpha[4];
            #pragma unroll
            for (int r = 0; r < 4; ++r) {
                float mx = sc[0][r];
                #pragma unroll
                for (int nt = 1; nt < 4; ++nt) mx = fmaxf(mx, sc[nt][r]);
                #pragma unroll
                for (int off = 1; off < 16; off <<= 1)
                    mx = fmaxf(mx, __shfl_xor(mx, off));
                mnew[r] = fmaxf(m_pr[r], mx);
                alpha[r] = __expf(m_pr[r] - mnew[r]);
                m_pr[r] = mnew[r];
            }

            float ps[4] = {0.f, 0.f, 0.f, 0.f};
            #pragma unroll
            for (int nt = 0; nt < 4; ++nt) {
                #pragma unroll
                for (int r = 0; r < 4; ++r) {
                    float pv = __expf(sc[nt][r] - mnew[r]);
                    ps[r] += pv;
                    sP[(mw + quad * 4 + r) * LDV + nt * 16 + lr] = f2bf(pv);
                }
            }
            #pragma unroll
            for (int r = 0; r < 4; ++r) {
                #pragma unroll
                for (int off = 1; off < 16; off <<= 1)
                    ps[r] += __shfl_xor(ps[r], off);
                l_run[r] = l_run[r] * alpha[r] + ps[r];
                if (lr == 0) sAlpha[mw + quad * 4 + r] = alpha[r];
            }
            __syncthreads();

            // O^T += VT_tile @ P^T ; wave owns dd-tiles 2w, 2w+1
            float a_col[4];
            #pragma unroll
            for (int nt = 0; nt < 4; ++nt) a_col[nt] = sAlpha[nt * 16 + lr];
            #pragma unroll
            for (int dt = 0; dt < 2; ++dt)
                #pragma unroll
                for (int nt = 0; nt < 4; ++nt)
                    #pragma unroll
                    for (int r = 0; r < 4; ++r)
                        oacc[dt][nt][r] *= a_col[nt];
            __builtin_amdgcn_s_setprio(1);
            #pragma unroll
            for (int kc = 0; kc < 2; ++kc) {
                bf16x8 bfr[4];
                #pragma unroll
                for (int nt = 0; nt < 4; ++nt)
                    bfr[nt] = *(const bf16x8*)(&sP[(nt * 16 + lr) * LDV + kc * 32 + quad * 8]);
                #pragma unroll
                for (int dt = 0; dt < 2; ++dt) {
                    bf16x8 af = *(const bf16x8*)(&sVt[((2 * w + dt) * 16 + lr) * LDV + kc * 32 + quad * 8]);
                    #pragma unroll
                    for (int nt = 0; nt < 4; ++nt)
                        oacc[dt][nt] = __builtin_amdgcn_mfma_f32_16x16x32_bf16(af, bfr[nt], oacc[dt][nt], 0, 0, 0);
                }
            }
            __builtin_amdgcn_s_setprio(0);
        }

        #pragma unroll
        for (int r = 0; r < 4; ++r)
            if (lr == 0) sL[mw + quad * 4 + r] = l_run[r];
        __syncthreads();

        // O^T regs -> sO (=sK) [m][dd] with 1/l scaling, then coalesced store
        float linv[4];
        #pragma unroll
        for (int nt = 0; nt < 4; ++nt) linv[nt] = 1.f / sL[nt * 16 + lr];
        #pragma unroll
        for (int dt = 0; dt < 2; ++dt) {
            int ddl = (2 * w + dt) * 16 + quad * 4;
            #pragma unroll
            for (int nt = 0; nt < 4; ++nt) {
                int ml = nt * 16 + lr;
                #pragma unroll
                for (int r = 0; r < 4; ++r)
                    sK[ml * LDP + ddl + r] = f2bf(oacc[dt][nt][r] * linv[nt]);
            }
        }
        __syncthreads();
        for (int c = t; c < 64 * 16; c += 256) {
            int m = c >> 4, dc = (c & 15) * 8;
            *(uint4*)(&O[(size_t)(q0 + m) * DD + base + dc]) =
                *(const uint4*)(&sK[m * LDP + dc]);
        }
        // next item's sK writes are ordered by the barrier at kt-loop top
    }
}

extern "C" void kernel_launch(void* const* d_in, const int* in_sizes, int n_in,
                              void* d_out, int out_size, void* d_ws, size_t ws_size,
                              hipStream_t stream) {
    const float* X    = (const float*)d_in[0];
    const float* mask = (const float*)d_in[1];
    const float* cosb = (const float*)d_in[2];
    const float* sinb = (const float*)d_in[3];
    const float* wq   = (const float*)d_in[4];
    const float* wk   = (const float*)d_in[5];
    const float* wv   = (const float*)d_in[6];
    const float* wo   = (const float*)d_in[7];
    float* out = (float*)d_out;

    char* ws = (char*)d_ws;
    uint16_t* Wt  = (uint16_t*)ws;                            // 32 MB
    uint16_t* Xbf = (uint16_t*)(ws + (size_t)33554432);       // 16 MB
    uint16_t* Q   = Xbf + (size_t)SS * DD;
    uint16_t* Kb  = Q  + (size_t)SS * DD;
    uint16_t* VT  = Kb + (size_t)SS * DD;                     // [D][S]
    uint16_t* AO  = Xbf;  // X dead after VT gemm; reuse for attention output

    dim3 tgrid(DD / 32, DD / 32), tblock(32, 8);
    dim3 ggrid(DD / 128, SS / 128), gblock(256);

    xconv_kernel<<<(SS * DD) / (256 * 8), 256, 0, stream>>>(X, Xbf);

    wtrans_kernel<<<tgrid, tblock, 0, stream>>>(wq, Wt);
    gemm_bt<<<ggrid, gblock, 0, stream>>>(Xbf, Wt, Q, SS, DD, DD);
    wtrans_kernel<<<tgrid, tblock, 0, stream>>>(wk, Wt);
    gemm_bt<<<ggrid, gblock, 0, stream>>>(Xbf, Wt, Kb, SS, DD, DD);
    wtrans_kernel<<<tgrid, tblock, 0, stream>>>(wv, Wt);
    // VT[d][s] = sum_k Wv[k][d] * X[s][k]  (A = Wv^T rows, Bt = X rows)
    gemm_bt<<<dim3(SS / 128, DD / 128), gblock, 0, stream>>>(Wt, Xbf, VT, DD, SS, DD);

    rope_kernel<<<(SS * 2048) / 256, 256, 0, stream>>>(Q, Kb, cosb, sinb);

    fattn_kernel<<<dim3(512), 256, 0, stream>>>(Q, Kb, VT, mask, AO);

    wtrans_kernel<<<tgrid, tblock, 0, stream>>>(wo, Wt);
    gemm_bt<<<ggrid, gblock, 0, stream>>>(AO, Wt, out, SS, DD, DD);
}